// Round 15
// baseline (212.087 us; speedup 1.0000x reference)
//
#include <hip/hip_runtime.h>
#include <stdint.h>

typedef float f4 __attribute__((ext_vector_type(4)));
typedef float f32x4 __attribute__((ext_vector_type(4)));
typedef _Float16 hq4 __attribute__((ext_vector_type(4)));
typedef _Float16 half8 __attribute__((ext_vector_type(8)));

#define DF 128    // input feature dim
#define HID 64    // hidden dim
#define EPB 4096  // edges per sort block (391 blocks of 512 threads, 8/thread)
#define CAP 5120  // slots per coarse bucket (avg 4096, max~4314 for seed-0 input)
#define SRCMASK 0x00FFFFFF

// ---------- prep: zero cur + repack W1 into MFMA B-fragment order (fp16) ----------
__global__ __launch_bounds__(256) void kPrep(const float* __restrict__ W1,
                                             _Float16* __restrict__ W1f,
                                             int* __restrict__ cur, int nbin) {
    int t = blockIdx.x * 256 + threadIdx.x;   // 8192 threads
    if (t < nbin) cur[t] = 0;
    if (t < 8192) {
        int j     = t & 7;
        int lane  = (t >> 3) & 63;
        int ntile = (t >> 9) & 3;
        int kstep = t >> 11;
        int k = kstep * 32 + (lane >> 4) * 8 + j;
        int n = ntile * 16 + (lane & 15);
        W1f[t] = (_Float16)W1[k * 64 + n];
    }
}

// ---------- single-pass bucket scatter with block-local counting sort ----------
__global__ __launch_bounds__(512) void kA3(const int* __restrict__ row,
                                           const int* __restrict__ col,
                                           const float* __restrict__ ew,
                                           int* __restrict__ cur,
                                           int2* __restrict__ tmp,
                                           int E, int nbin) {
    __shared__ int hist[512];
    __shared__ int pref[512];
    __shared__ int lbase[512];
    __shared__ int2 sv[EPB];   // 32 KB
    __shared__ int  sa[EPB];   // 16 KB
    int b = blockIdx.x, t = threadIdx.x;
    hist[t] = 0;
    __syncthreads();
    int s = b * EPB, e = min(E, s + EPB);
    int cnt = e - s;
    int  mybin[8], myrank[8];
    int2 myv[8];
#pragma unroll
    for (int k = 0; k < 8; ++k) {
        int i = s + t + k * 512;
        mybin[k] = -1;
        if (i < e) {
            int c = col[i];
            int bin = c >> 8;
            myv[k].x = row[i] | ((c & 255) << 24);   // src 17b | fine-col<<24
            myv[k].y = __float_as_int(ew[i]);
            mybin[k] = bin;
            myrank[k] = atomicAdd(&hist[bin], 1);
        }
    }
    __syncthreads();
    int val = hist[t];
    lbase[t] = val ? atomicAdd(&cur[t], val) + t * CAP : 0;  // absolute base (t==bin)
    for (int d = 1; d < 512; d <<= 1) {
        int x = (t >= d) ? hist[t - d] : 0;
        __syncthreads();
        hist[t] += x;
        __syncthreads();
    }
    pref[t] = hist[t] - val;   // exclusive prefix within block
    __syncthreads();
#pragma unroll
    for (int k = 0; k < 8; ++k) {
        if (mybin[k] >= 0) {
            int pos = pref[mybin[k]] + myrank[k];
            sv[pos] = myv[k];
            sa[pos] = lbase[mybin[k]] + myrank[k];
        }
    }
    __syncthreads();
    for (int i = t; i < cnt; i += 512) tmp[sa[i]] = sv[i];
}

// ---------- B: single global read, LDS fine-sort, coalesced write ----------
// edata keeps the fine-col byte in .x (agg masks, k_out uses it).
__global__ __launch_bounds__(512) void kB(const int2* __restrict__ tmp,
                                          const int* __restrict__ cur,
                                          int2* __restrict__ edata,
                                          int2* __restrict__ offse,
                                          float* __restrict__ dinv,
                                          int N) {
    __shared__ int2 raw[CAP];      // 40 KB
    __shared__ int2 sorted[CAP];   // 40 KB
    __shared__ int hist[256];
    __shared__ int basel[256];
    __shared__ float degl[256];
    int bin = blockIdx.x, t = threadIdx.x;
    int s = bin * CAP;
    int cnt = min(cur[bin], CAP);

    if (t < 256) { hist[t] = 0; degl[t] = 0.f; }
    __syncthreads();
    // one coalesced read; hist + degree on the fly
    for (int i = t; i < cnt; i += 512) {
        int2 pr = tmp[s + i];
        raw[i] = pr;
        int lo = ((unsigned)pr.x) >> 24;
        atomicAdd(&hist[lo], 1);
        atomicAdd(&degl[lo], __int_as_float(pr.y));
    }
    __syncthreads();
    int val = (t < 256) ? hist[t] : 0;
    __syncthreads();
    for (int d = 1; d < 256; d <<= 1) {
        int x = (t < 256 && t >= d) ? hist[t - d] : 0;
        __syncthreads();
        if (t < 256) hist[t] += x;
        __syncthreads();
    }
    if (t < 256) basel[t] = hist[t] - val;   // exclusive prefix (local)
    __syncthreads();
    // scatter LDS -> LDS sorted
    for (int i = t; i < cnt; i += 512) {
        int2 pr = raw[i];
        int lo = ((unsigned)pr.x) >> 24;
        int pos = atomicAdd(&basel[lo], 1);
        sorted[pos] = pr;                    // keep fine-col byte
    }
    __syncthreads();
    // coalesced write-out
    for (int i = t; i < cnt; i += 512) edata[s + i] = sorted[i];
    int c = bin * 256 + t;
    if (t < 256 && c < N) {
        int end = basel[t];                  // loff + count
        int2 oe;
        oe.x = s + end - val;
        oe.y = s + end;
        offse[c] = oe;
        dinv[c] = rsqrtf(1.0f + degl[t]);    // deg >= 1 (self-loop)
    }
}

// ---------- h' = dinv[n] * (x @ W1)[n] via MFMA fp16, fp16 store ----------
__global__ __launch_bounds__(256) void k_gemm1(const float* __restrict__ x,
                                               const _Float16* __restrict__ W1f,
                                               const float* __restrict__ dinv,
                                               _Float16* __restrict__ h, int N) {
    int wave  = (blockIdx.x * 256 + threadIdx.x) >> 6;
    int nstrip = (N + 15) >> 4;
    if (wave >= nstrip) return;
    int node0 = wave << 4;
    int l = threadIdx.x & 63;
    int quad = l >> 4;
    int m = l & 15;
    int r = node0 + m;
    if (r >= N) r = N - 1;   // clamp (harmless duplicate load)

    const half8* bfrag = (const half8*)W1f;
    f32x4 acc[4];
#pragma unroll
    for (int nt = 0; nt < 4; ++nt) acc[nt] = (f32x4)(0.f);

#pragma unroll
    for (int kstep = 0; kstep < 4; ++kstep) {
        const f4* xr = (const f4*)(x + (size_t)r * DF + kstep * 32 + quad * 8);
        f4 a0 = xr[0], a1 = xr[1];
        half8 af;
        af[0] = (_Float16)a0.x; af[1] = (_Float16)a0.y;
        af[2] = (_Float16)a0.z; af[3] = (_Float16)a0.w;
        af[4] = (_Float16)a1.x; af[5] = (_Float16)a1.y;
        af[6] = (_Float16)a1.z; af[7] = (_Float16)a1.w;
#pragma unroll
        for (int nt = 0; nt < 4; ++nt) {
            half8 bf = bfrag[(kstep * 4 + nt) * 64 + l];
            acc[nt] = __builtin_amdgcn_mfma_f32_16x16x32_f16(af, bf, acc[nt], 0, 0, 0);
        }
    }

    float dv[4];
    int nodeb = node0 + quad * 4;
#pragma unroll
    for (int reg = 0; reg < 4; ++reg)
        dv[reg] = (nodeb + reg < N) ? dinv[nodeb + reg] : 0.f;
#pragma unroll
    for (int nt = 0; nt < 4; ++nt) {
#pragma unroll
        for (int reg = 0; reg < 4; ++reg) {
            int node = nodeb + reg;
            if (node < N)
                h[(unsigned)node * 64u + (unsigned)(nt * 16 + m)] =
                    (_Float16)(dv[reg] * acc[nt][reg]);
        }
    }
}

// ---------- fused layer-1 aggregate + relu + @W2 : one wave per node ----------
// quad-edge scheme; edata.x carries fine-col in the high byte -> mask for src.
__global__ __launch_bounds__(256) void k_agg_h2(const int2* __restrict__ offse,
                                                const int2* __restrict__ edata,
                                                const float* __restrict__ dinv,
                                                const _Float16* __restrict__ h,
                                                const float* __restrict__ b1,
                                                const float* __restrict__ W2,
                                                float* __restrict__ h2p, int N) {
    __shared__ int2 stage[4][64];
    int wv = threadIdx.x >> 6;
    int v = blockIdx.x * 4 + wv;
    if (v >= N) return;
    int l = threadIdx.x & 63;
    int sub = l >> 4;                  // edge slot 0..3
    unsigned fq = (unsigned)(l & 15);  // feature quad: features 4fq..4fq+3
    const hq4* hp = (const hq4*)h;     // hp[(src<<4)|fq] = 4 features (8B)

    float di = dinv[v];
    float a0 = 0.f, a1 = 0.f, a2 = 0.f, a3 = 0.f;
    if (sub == 0) {                    // self-loop: h'[v] = di*h[v]
        hq4 sv4 = hp[((unsigned)v << 4) | fq];
        a0 = (float)sv4.x; a1 = (float)sv4.y;
        a2 = (float)sv4.z; a3 = (float)sv4.w;
    }

    int2 oe = offse[v];
    for (int base = oe.x; base < oe.y; base += 64) {
        int idx = base + l;
        int2 pr;
        pr.x = 0; pr.y = 0;            // w=0 for lanes past the end
        if (idx < oe.y) pr = edata[idx];
        stage[wv][l] = pr;             // wave-private row; no block barrier needed
        int cnt = min(64, oe.y - base);
        int steps = (cnt + 3) >> 2;
#pragma unroll 4
        for (int k = 0; k < steps; ++k) {
            int2 em = stage[wv][4 * k + sub];
            float w = __int_as_float(em.y);
            unsigned src = (unsigned)(em.x & SRCMASK);
            hq4 hv = hp[(src << 4) | fq];
            a0 += w * (float)hv.x;
            a1 += w * (float)hv.y;
            a2 += w * (float)hv.z;
            a3 += w * (float)hv.w;
        }
    }
    // reduce over the 4 edge slots (lanes sharing fq)
    a0 += __shfl_xor(a0, 16); a1 += __shfl_xor(a1, 16);
    a2 += __shfl_xor(a2, 16); a3 += __shfl_xor(a3, 16);
    a0 += __shfl_xor(a0, 32); a1 += __shfl_xor(a1, 32);
    a2 += __shfl_xor(a2, 32); a3 += __shfl_xor(a3, 32);

    if (sub == 0) {
        a0 = di * a0; a1 = di * a1; a2 = di * a2; a3 = di * a3;
        float s = fmaxf(a0 + b1[4 * fq], 0.f)     * W2[4 * fq]
                + fmaxf(a1 + b1[4 * fq + 1], 0.f) * W2[4 * fq + 1]
                + fmaxf(a2 + b1[4 * fq + 2], 0.f) * W2[4 * fq + 2]
                + fmaxf(a3 + b1[4 * fq + 3], 0.f) * W2[4 * fq + 3];
        s += __shfl_down(s, 8);
        s += __shfl_down(s, 4);
        s += __shfl_down(s, 2);
        s += __shfl_down(s, 1);
        if (fq == 0) h2p[v] = di * s;   // store dinv-scaled hidden
    }
}

// ---------- layer-2: edge-parallel per bucket, LDS accumulate by fine col ----------
__global__ __launch_bounds__(256) void k_out(const int* __restrict__ cur,
                                             const int2* __restrict__ edata,
                                             const float* __restrict__ dinv,
                                             const float* __restrict__ h2p,
                                             const float* __restrict__ b2,
                                             float* __restrict__ out, int N) {
    __shared__ float acc[256];
    int bin = blockIdx.x, t = threadIdx.x;
    acc[t] = 0.f;
    __syncthreads();
    int s = bin * CAP;
    int cnt = min(cur[bin], CAP);
    for (int i = s + t; i < s + cnt; i += 256) {
        int2 pr = edata[i];
        int lo = ((unsigned)pr.x) >> 24;
        float val = __int_as_float(pr.y) * h2p[(unsigned)(pr.x & SRCMASK)];
        atomicAdd(&acc[lo], val);
    }
    __syncthreads();
    int v = bin * 256 + t;
    if (v < N) out[v] = b2[0] + dinv[v] * (h2p[v] + acc[t]);
}

extern "C" void kernel_launch(void* const* d_in, const int* in_sizes, int n_in,
                              void* d_out, int out_size, void* d_ws, size_t ws_size,
                              hipStream_t stream) {
    const float* x  = (const float*)d_in[0];
    const int*   ei = (const int*)d_in[1];
    const float* ew = (const float*)d_in[2];
    const float* W1 = (const float*)d_in[3];
    const float* b1 = (const float*)d_in[4];
    const float* W2 = (const float*)d_in[5];
    const float* b2 = (const float*)d_in[6];
    float* out = (float*)d_out;

    const int N = in_sizes[0] / DF;       // 100000
    const int E = in_sizes[2];            // 1600000
    const int* row = ei;                  // sources
    const int* col = ei + E;              // targets

    const int nbin = (N + 255) / 256;     // 391 coarse buckets
    const int nblk = (E + EPB - 1) / EPB; // 391 sort/scatter blocks

    // ---- workspace layout, ~34 MB (proven-safe budget ~40 MB) ----
    // edata and tmp are CAP-gapped (nbin*CAP entries each). tmp (16 MB) aliases
    // h (12.8 MB fp16): tmp dead after kB, h first written by k_gemm1 (after kB).
    size_t    gsz   = (size_t)nbin * CAP;                 // gapped entry count
    int*      w32   = (int*)d_ws;
    int2*     edata = (int2*)w32;                         // gsz int2 = 16.0 MB
    int*      shreg = w32 + (size_t)2 * gsz;
    int2*     tmp   = (int2*)shreg;                       // build phase (16.0 MB)
    _Float16* h     = (_Float16*)shreg;                   // compute phase (12.8 MB)
    int*      p     = shreg + (size_t)2 * gsz;
    int*      cur   = p;  p += ((nbin) + 3) & ~3;         // nbin
    float*    dinv  = (float*)p;  p += N;                 // N
    float*    h2p   = (float*)p;  p += N;                 // N
    int2*     offse = (int2*)p;   p += 2 * N;             // N int2
    _Float16* W1f   = (_Float16*)p;                       // 8192 fp16 = 16 KB

    const int B = 256;
    int nstrip = (N + 15) / 16;
    int gGm  = (nstrip + 3) / 4;           // 4 waves (strips) per block
    int gAgg = (N + 3) / 4;

    kPrep<<<32, B, 0, stream>>>(W1, W1f, cur, nbin);
    kA3<<<nblk, 512, 0, stream>>>(row, col, ew, cur, tmp, E, nbin);
    kB<<<nbin, 512, 0, stream>>>(tmp, cur, edata, offse, dinv, N);
    k_gemm1<<<gGm, B, 0, stream>>>(x, W1f, dinv, h, N);
    k_agg_h2<<<gAgg, B, 0, stream>>>(offse, edata, dinv, h, b1, W2, h2p, N);
    k_out<<<nbin, B, 0, stream>>>(cur, edata, dinv, h2p, b2, out, N);
}

// Round 16
// 211.197 us; speedup vs baseline: 1.0042x; 1.0042x over previous
//
#include <hip/hip_runtime.h>
#include <stdint.h>

typedef float f4 __attribute__((ext_vector_type(4)));
typedef float f32x4 __attribute__((ext_vector_type(4)));
typedef _Float16 hq4 __attribute__((ext_vector_type(4)));
typedef _Float16 half8 __attribute__((ext_vector_type(8)));

#define DF 128    // input feature dim
#define HID 64    // hidden dim
#define EPB 4096  // edges per sort block (391 blocks of 512 threads, 8/thread)
#define CAP 5120  // slots per coarse bucket (avg 4096, max~4314 for seed-0 input)

// ---------- prep: zero cur + repack W1 into MFMA B-fragment order (fp16) ----------
__global__ __launch_bounds__(256) void kPrep(const float* __restrict__ W1,
                                             _Float16* __restrict__ W1f,
                                             int* __restrict__ cur, int nbin) {
    int t = blockIdx.x * 256 + threadIdx.x;   // 8192 threads
    if (t < nbin) cur[t] = 0;
    if (t < 8192) {
        int j     = t & 7;
        int lane  = (t >> 3) & 63;
        int ntile = (t >> 9) & 3;
        int kstep = t >> 11;
        int k = kstep * 32 + (lane >> 4) * 8 + j;
        int n = ntile * 16 + (lane & 15);
        W1f[t] = (_Float16)W1[k * 64 + n];
    }
}

// ---------- single-pass bucket scatter with block-local counting sort ----------
__global__ __launch_bounds__(512) void kA3(const int* __restrict__ row,
                                           const int* __restrict__ col,
                                           const float* __restrict__ ew,
                                           int* __restrict__ cur,
                                           int2* __restrict__ tmp,
                                           int E, int nbin) {
    __shared__ int hist[512];
    __shared__ int pref[512];
    __shared__ int lbase[512];
    __shared__ int2 sv[EPB];   // 32 KB
    __shared__ int  sa[EPB];   // 16 KB
    int b = blockIdx.x, t = threadIdx.x;
    hist[t] = 0;
    __syncthreads();
    int s = b * EPB, e = min(E, s + EPB);
    int cnt = e - s;
    int  mybin[8], myrank[8];
    int2 myv[8];
#pragma unroll
    for (int k = 0; k < 8; ++k) {
        int i = s + t + k * 512;
        mybin[k] = -1;
        if (i < e) {
            int c = col[i];
            int bin = c >> 8;
            myv[k].x = row[i] | ((c & 255) << 24);   // src 17b | fine-col<<24
            myv[k].y = __float_as_int(ew[i]);
            mybin[k] = bin;
            myrank[k] = atomicAdd(&hist[bin], 1);
        }
    }
    __syncthreads();
    int val = hist[t];
    lbase[t] = val ? atomicAdd(&cur[t], val) + t * CAP : 0;  // absolute base (t==bin)
    for (int d = 1; d < 512; d <<= 1) {
        int x = (t >= d) ? hist[t - d] : 0;
        __syncthreads();
        hist[t] += x;
        __syncthreads();
    }
    pref[t] = hist[t] - val;   // exclusive prefix within block
    __syncthreads();
#pragma unroll
    for (int k = 0; k < 8; ++k) {
        if (mybin[k] >= 0) {
            int pos = pref[mybin[k]] + myrank[k];
            sv[pos] = myv[k];
            sa[pos] = lbase[mybin[k]] + myrank[k];
        }
    }
    __syncthreads();
    for (int i = t; i < cnt; i += 512) tmp[sa[i]] = sv[i];
}

// ---------- B: fine sort in LDS, coalesced edata write, fused deg/rsqrt ----------
__global__ __launch_bounds__(256) void kB(const int2* __restrict__ tmp,
                                          const int* __restrict__ cur,
                                          int2* __restrict__ edata,
                                          int2* __restrict__ offse,
                                          float* __restrict__ dinv,
                                          int N) {
    __shared__ int hist[256];
    __shared__ int basel[256];
    __shared__ int startl[256];
    __shared__ float degl[256];
    __shared__ int2 sorted[CAP];   // 40 KB
    int bin = blockIdx.x, t = threadIdx.x;
    int s = bin * CAP;
    int cnt = min(cur[bin], CAP);
    int e = s + cnt;

    hist[t] = 0;
    degl[t] = 0.f;
    __syncthreads();
    for (int i = s + t; i < e; i += 256) {
        int2 pr = tmp[i];
        int lo = ((unsigned)pr.x) >> 24;
        atomicAdd(&hist[lo], 1);
        atomicAdd(&degl[lo], __int_as_float(pr.y));
    }
    __syncthreads();
    int val = hist[t];
    __syncthreads();
    for (int d = 1; d < 256; d <<= 1) {
        int x = (t >= d) ? hist[t - d] : 0;
        __syncthreads();
        hist[t] += x;
        __syncthreads();
    }
    int loff = hist[t] - val;      // exclusive prefix within bucket (local)
    startl[t] = s + loff;
    basel[t]  = loff;
    __syncthreads();
    for (int i = s + t; i < e; i += 256) {
        int2 pr = tmp[i];
        int lo = ((unsigned)pr.x) >> 24;
        int pos = atomicAdd(&basel[lo], 1);
        int2 o;
        o.x = pr.x & 0x00FFFFFF;
        o.y = pr.y;
        sorted[pos] = o;
    }
    __syncthreads();
    for (int i = t; i < cnt; i += 256) edata[s + i] = sorted[i];
    int c = bin * 256 + t;
    if (c < N) {
        int2 oe;
        oe.x = startl[t];
        oe.y = startl[t] + val;
        offse[c] = oe;
        dinv[c] = rsqrtf(1.0f + degl[t]);   // deg >= 1 (self-loop)
    }
}

// ---------- h' = dinv[n] * (x @ W1)[n] via MFMA fp16, fp16 store ----------
__global__ __launch_bounds__(256) void k_gemm1(const float* __restrict__ x,
                                               const _Float16* __restrict__ W1f,
                                               const float* __restrict__ dinv,
                                               _Float16* __restrict__ h, int N) {
    int wave  = (blockIdx.x * 256 + threadIdx.x) >> 6;
    int nstrip = (N + 15) >> 4;
    if (wave >= nstrip) return;
    int node0 = wave << 4;
    int l = threadIdx.x & 63;
    int quad = l >> 4;
    int m = l & 15;
    int r = node0 + m;
    if (r >= N) r = N - 1;   // clamp (harmless duplicate load)

    const half8* bfrag = (const half8*)W1f;
    f32x4 acc[4];
#pragma unroll
    for (int nt = 0; nt < 4; ++nt) acc[nt] = (f32x4)(0.f);

#pragma unroll
    for (int kstep = 0; kstep < 4; ++kstep) {
        const f4* xr = (const f4*)(x + (size_t)r * DF + kstep * 32 + quad * 8);
        f4 a0 = xr[0], a1 = xr[1];
        half8 af;
        af[0] = (_Float16)a0.x; af[1] = (_Float16)a0.y;
        af[2] = (_Float16)a0.z; af[3] = (_Float16)a0.w;
        af[4] = (_Float16)a1.x; af[5] = (_Float16)a1.y;
        af[6] = (_Float16)a1.z; af[7] = (_Float16)a1.w;
#pragma unroll
        for (int nt = 0; nt < 4; ++nt) {
            half8 bf = bfrag[(kstep * 4 + nt) * 64 + l];
            acc[nt] = __builtin_amdgcn_mfma_f32_16x16x32_f16(af, bf, acc[nt], 0, 0, 0);
        }
    }

    float dv[4];
    int nodeb = node0 + quad * 4;
#pragma unroll
    for (int reg = 0; reg < 4; ++reg)
        dv[reg] = (nodeb + reg < N) ? dinv[nodeb + reg] : 0.f;
#pragma unroll
    for (int nt = 0; nt < 4; ++nt) {
#pragma unroll
        for (int reg = 0; reg < 4; ++reg) {
            int node = nodeb + reg;
            if (node < N)
                h[(unsigned)node * 64u + (unsigned)(nt * 16 + m)] =
                    (_Float16)(dv[reg] * acc[nt][reg]);
        }
    }
}

// ---------- fused layer-1 aggregate + relu + @W2 : one wave per node ----------
// quad-edge scheme: lane owns feature quad fq=l&15; slot sub=l>>4 processes
// edges 4k+sub. Chunk load issued FIRST so it overlaps the self-loop gather;
// exact per-slot loop bound masks off tail dummy gathers.
__global__ __launch_bounds__(256) void k_agg_h2(const int2* __restrict__ offse,
                                                const int2* __restrict__ edata,
                                                const float* __restrict__ dinv,
                                                const _Float16* __restrict__ h,
                                                const float* __restrict__ b1,
                                                const float* __restrict__ W2,
                                                float* __restrict__ h2p, int N) {
    __shared__ int2 stage[4][64];
    int wv = threadIdx.x >> 6;
    int v = blockIdx.x * 4 + wv;
    if (v >= N) return;
    int l = threadIdx.x & 63;
    int sub = l >> 4;                  // edge slot 0..3
    unsigned fq = (unsigned)(l & 15);  // feature quad: features 4fq..4fq+3
    const hq4* hp = (const hq4*)h;     // hp[(src<<4)|fq] = 4 features (8B)

    // issue first chunk + dinv + self-loop loads together
    int2 oe = offse[v];
    float di = dinv[v];
    int idx0 = oe.x + l;
    int2 pr0;
    pr0.x = 0; pr0.y = 0;
    if (idx0 < oe.y) pr0 = edata[idx0];

    float a0 = 0.f, a1 = 0.f, a2 = 0.f, a3 = 0.f;
    if (sub == 0) {                    // self-loop: h'[v] = di*h[v]
        hq4 sv4 = hp[((unsigned)v << 4) | fq];
        a0 = (float)sv4.x; a1 = (float)sv4.y;
        a2 = (float)sv4.z; a3 = (float)sv4.w;
    }

    for (int base = oe.x; base < oe.y; base += 64) {
        int2 pr = pr0;
        if (base != oe.x) {
            int idx = base + l;
            pr.x = 0; pr.y = 0;
            if (idx < oe.y) pr = edata[idx];
        }
        stage[wv][l] = pr;             // wave-private row; no block barrier needed
        int cnt = min(64, oe.y - base);
        for (int k = 0; 4 * k + sub < cnt; ++k) {
            int2 em = stage[wv][4 * k + sub];
            float w = __int_as_float(em.y);
            hq4 hv = hp[((unsigned)em.x << 4) | fq];
            a0 += w * (float)hv.x;
            a1 += w * (float)hv.y;
            a2 += w * (float)hv.z;
            a3 += w * (float)hv.w;
        }
    }
    // reduce over the 4 edge slots (lanes sharing fq)
    a0 += __shfl_xor(a0, 16); a1 += __shfl_xor(a1, 16);
    a2 += __shfl_xor(a2, 16); a3 += __shfl_xor(a3, 16);
    a0 += __shfl_xor(a0, 32); a1 += __shfl_xor(a1, 32);
    a2 += __shfl_xor(a2, 32); a3 += __shfl_xor(a3, 32);

    if (sub == 0) {
        a0 = di * a0; a1 = di * a1; a2 = di * a2; a3 = di * a3;
        float s = fmaxf(a0 + b1[4 * fq], 0.f)     * W2[4 * fq]
                + fmaxf(a1 + b1[4 * fq + 1], 0.f) * W2[4 * fq + 1]
                + fmaxf(a2 + b1[4 * fq + 2], 0.f) * W2[4 * fq + 2]
                + fmaxf(a3 + b1[4 * fq + 3], 0.f) * W2[4 * fq + 3];
        s += __shfl_down(s, 8);
        s += __shfl_down(s, 4);
        s += __shfl_down(s, 2);
        s += __shfl_down(s, 1);
        if (fq == 0) h2p[v] = di * s;   // store dinv-scaled hidden
    }
}

// ---------- layer-2 aggregation: 16 lanes per node; h2p pre-scaled ----------
__global__ __launch_bounds__(256) void k_out(const int2* __restrict__ offse,
                                             const int2* __restrict__ edata,
                                             const float* __restrict__ dinv,
                                             const float* __restrict__ h2p,
                                             const float* __restrict__ b2,
                                             float* __restrict__ out, int N) {
    int t = blockIdx.x * 256 + threadIdx.x;
    int v = t >> 4;
    if (v >= N) return;
    int c = t & 15;
    int2 oe = offse[v];
    float s = 0.f;
    for (int i = oe.x + c; i < oe.y; i += 16) {
        int2 pr = edata[i];
        s += __int_as_float(pr.y) * h2p[(unsigned)pr.x];
    }
    s += __shfl_down(s, 8);
    s += __shfl_down(s, 4);
    s += __shfl_down(s, 2);
    s += __shfl_down(s, 1);
    if (c == 0) {
        float di = dinv[v];
        out[v] = b2[0] + di * (h2p[v] + s);   // h2p[v] = di*h2[v]
    }
}

extern "C" void kernel_launch(void* const* d_in, const int* in_sizes, int n_in,
                              void* d_out, int out_size, void* d_ws, size_t ws_size,
                              hipStream_t stream) {
    const float* x  = (const float*)d_in[0];
    const int*   ei = (const int*)d_in[1];
    const float* ew = (const float*)d_in[2];
    const float* W1 = (const float*)d_in[3];
    const float* b1 = (const float*)d_in[4];
    const float* W2 = (const float*)d_in[5];
    const float* b2 = (const float*)d_in[6];
    float* out = (float*)d_out;

    const int N = in_sizes[0] / DF;       // 100000
    const int E = in_sizes[2];            // 1600000
    const int* row = ei;                  // sources
    const int* col = ei + E;              // targets

    const int nbin = (N + 255) / 256;     // 391 coarse buckets
    const int nblk = (E + EPB - 1) / EPB; // 391 sort/scatter blocks

    // ---- workspace layout, ~34 MB (proven-safe budget ~40 MB) ----
    size_t    gsz   = (size_t)nbin * CAP;                 // gapped entry count
    int*      w32   = (int*)d_ws;
    int2*     edata = (int2*)w32;                         // gsz int2 = 16.0 MB
    int*      shreg = w32 + (size_t)2 * gsz;
    int2*     tmp   = (int2*)shreg;                       // build phase (16.0 MB)
    _Float16* h     = (_Float16*)shreg;                   // compute phase (12.8 MB)
    int*      p     = shreg + (size_t)2 * gsz;
    int*      cur   = p;  p += ((nbin) + 3) & ~3;         // nbin
    float*    dinv  = (float*)p;  p += N;                 // N
    float*    h2p   = (float*)p;  p += N;                 // N
    int2*     offse = (int2*)p;   p += 2 * N;             // N int2
    _Float16* W1f   = (_Float16*)p;                       // 8192 fp16 = 16 KB

    const int B = 256;
    int nstrip = (N + 15) / 16;
    int gGm  = (nstrip + 3) / 4;           // 4 waves (strips) per block
    int gAgg = (N + 3) / 4;
    int gN16 = (N * 16 + B - 1) / B;

    kPrep<<<32, B, 0, stream>>>(W1, W1f, cur, nbin);
    kA3<<<nblk, 512, 0, stream>>>(row, col, ew, cur, tmp, E, nbin);
    kB<<<nbin, B, 0, stream>>>(tmp, cur, edata, offse, dinv, N);
    k_gemm1<<<gGm, B, 0, stream>>>(x, W1f, dinv, h, N);
    k_agg_h2<<<gAgg, B, 0, stream>>>(offse, edata, dinv, h, b1, W2, h2p, N);
    k_out<<<gN16, B, 0, stream>>>(offse, edata, dinv, h2p, b2, out, N);
}

// Round 17
// 209.577 us; speedup vs baseline: 1.0120x; 1.0077x over previous
//
#include <hip/hip_runtime.h>
#include <stdint.h>

typedef float f4 __attribute__((ext_vector_type(4)));
typedef float f32x4 __attribute__((ext_vector_type(4)));
typedef _Float16 hq4 __attribute__((ext_vector_type(4)));
typedef _Float16 half8 __attribute__((ext_vector_type(8)));

#define DF 128    // input feature dim
#define HID 64    // hidden dim
#define EPB 3125  // edges per sort block: 1.6M/3125 = 512 blocks = 2/CU, all resident
#define CAP 5120  // slots per coarse bucket (avg 4096, max~4314 for seed-0 input)

// ---------- prep: zero cur + repack W1 into MFMA B-fragment order (fp16) ----------
__global__ __launch_bounds__(256) void kPrep(const float* __restrict__ W1,
                                             _Float16* __restrict__ W1f,
                                             int* __restrict__ cur, int nbin) {
    int t = blockIdx.x * 256 + threadIdx.x;   // 8192 threads
    if (t < nbin) cur[t] = 0;
    if (t < 8192) {
        int j     = t & 7;
        int lane  = (t >> 3) & 63;
        int ntile = (t >> 9) & 3;
        int kstep = t >> 11;
        int k = kstep * 32 + (lane >> 4) * 8 + j;
        int n = ntile * 16 + (lane & 15);
        W1f[t] = (_Float16)W1[k * 64 + n];
    }
}

// ---------- single-pass bucket scatter with block-local counting sort ----------
// 512 blocks x 3125 edges: every block resident (2/CU), perfectly balanced.
__global__ __launch_bounds__(512) void kA3(const int* __restrict__ row,
                                           const int* __restrict__ col,
                                           const float* __restrict__ ew,
                                           int* __restrict__ cur,
                                           int2* __restrict__ tmp,
                                           int E, int nbin) {
    __shared__ int hist[512];
    __shared__ int pref[512];
    __shared__ int lbase[512];
    __shared__ int2 sv[EPB];   // 25 KB
    __shared__ int  sa[EPB];   // 12.5 KB
    int b = blockIdx.x, t = threadIdx.x;
    hist[t] = 0;
    __syncthreads();
    int s = b * EPB, e = min(E, s + EPB);
    int cnt = e - s;
    int  mybin[7], myrank[7];
    int2 myv[7];
#pragma unroll
    for (int k = 0; k < 7; ++k) {
        int i = s + t + k * 512;
        mybin[k] = -1;
        if (i < e) {
            int c = col[i];
            int bin = c >> 8;
            myv[k].x = row[i] | ((c & 255) << 24);   // src 17b | fine-col<<24
            myv[k].y = __float_as_int(ew[i]);
            mybin[k] = bin;
            myrank[k] = atomicAdd(&hist[bin], 1);
        }
    }
    __syncthreads();
    int val = hist[t];
    lbase[t] = val ? atomicAdd(&cur[t], val) + t * CAP : 0;  // absolute base (t==bin)
    for (int d = 1; d < 512; d <<= 1) {
        int x = (t >= d) ? hist[t - d] : 0;
        __syncthreads();
        hist[t] += x;
        __syncthreads();
    }
    pref[t] = hist[t] - val;   // exclusive prefix within block
    __syncthreads();
#pragma unroll
    for (int k = 0; k < 7; ++k) {
        if (mybin[k] >= 0) {
            int pos = pref[mybin[k]] + myrank[k];
            sv[pos] = myv[k];
            sa[pos] = lbase[mybin[k]] + myrank[k];
        }
    }
    __syncthreads();
    for (int i = t; i < cnt; i += 512) tmp[sa[i]] = sv[i];
}

// ---------- B: fine sort in LDS, coalesced edata write, fused deg/rsqrt ----------
__global__ __launch_bounds__(256) void kB(const int2* __restrict__ tmp,
                                          const int* __restrict__ cur,
                                          int2* __restrict__ edata,
                                          int2* __restrict__ offse,
                                          float* __restrict__ dinv,
                                          int N) {
    __shared__ int hist[256];
    __shared__ int basel[256];
    __shared__ int startl[256];
    __shared__ float degl[256];
    __shared__ int2 sorted[CAP];   // 40 KB
    int bin = blockIdx.x, t = threadIdx.x;
    int s = bin * CAP;
    int cnt = min(cur[bin], CAP);
    int e = s + cnt;

    hist[t] = 0;
    degl[t] = 0.f;
    __syncthreads();
    for (int i = s + t; i < e; i += 256) {
        int2 pr = tmp[i];
        int lo = ((unsigned)pr.x) >> 24;
        atomicAdd(&hist[lo], 1);
        atomicAdd(&degl[lo], __int_as_float(pr.y));
    }
    __syncthreads();
    int val = hist[t];
    __syncthreads();
    for (int d = 1; d < 256; d <<= 1) {
        int x = (t >= d) ? hist[t - d] : 0;
        __syncthreads();
        hist[t] += x;
        __syncthreads();
    }
    int loff = hist[t] - val;      // exclusive prefix within bucket (local)
    startl[t] = s + loff;
    basel[t]  = loff;
    __syncthreads();
    for (int i = s + t; i < e; i += 256) {
        int2 pr = tmp[i];
        int lo = ((unsigned)pr.x) >> 24;
        int pos = atomicAdd(&basel[lo], 1);
        int2 o;
        o.x = pr.x & 0x00FFFFFF;
        o.y = pr.y;
        sorted[pos] = o;
    }
    __syncthreads();
    for (int i = t; i < cnt; i += 256) edata[s + i] = sorted[i];
    int c = bin * 256 + t;
    if (c < N) {
        int2 oe;
        oe.x = startl[t];
        oe.y = startl[t] + val;
        offse[c] = oe;
        dinv[c] = rsqrtf(1.0f + degl[t]);   // deg >= 1 (self-loop)
    }
}

// ---------- h' = dinv[n] * (x @ W1)[n] via MFMA fp16, fp16 store ----------
__global__ __launch_bounds__(256) void k_gemm1(const float* __restrict__ x,
                                               const _Float16* __restrict__ W1f,
                                               const float* __restrict__ dinv,
                                               _Float16* __restrict__ h, int N) {
    int wave  = (blockIdx.x * 256 + threadIdx.x) >> 6;
    int nstrip = (N + 15) >> 4;
    if (wave >= nstrip) return;
    int node0 = wave << 4;
    int l = threadIdx.x & 63;
    int quad = l >> 4;
    int m = l & 15;
    int r = node0 + m;
    if (r >= N) r = N - 1;   // clamp (harmless duplicate load)

    const half8* bfrag = (const half8*)W1f;
    f32x4 acc[4];
#pragma unroll
    for (int nt = 0; nt < 4; ++nt) acc[nt] = (f32x4)(0.f);

#pragma unroll
    for (int kstep = 0; kstep < 4; ++kstep) {
        const f4* xr = (const f4*)(x + (size_t)r * DF + kstep * 32 + quad * 8);
        f4 a0 = xr[0], a1 = xr[1];
        half8 af;
        af[0] = (_Float16)a0.x; af[1] = (_Float16)a0.y;
        af[2] = (_Float16)a0.z; af[3] = (_Float16)a0.w;
        af[4] = (_Float16)a1.x; af[5] = (_Float16)a1.y;
        af[6] = (_Float16)a1.z; af[7] = (_Float16)a1.w;
#pragma unroll
        for (int nt = 0; nt < 4; ++nt) {
            half8 bf = bfrag[(kstep * 4 + nt) * 64 + l];
            acc[nt] = __builtin_amdgcn_mfma_f32_16x16x32_f16(af, bf, acc[nt], 0, 0, 0);
        }
    }

    float dv[4];
    int nodeb = node0 + quad * 4;
#pragma unroll
    for (int reg = 0; reg < 4; ++reg)
        dv[reg] = (nodeb + reg < N) ? dinv[nodeb + reg] : 0.f;
#pragma unroll
    for (int nt = 0; nt < 4; ++nt) {
#pragma unroll
        for (int reg = 0; reg < 4; ++reg) {
            int node = nodeb + reg;
            if (node < N)
                h[(unsigned)node * 64u + (unsigned)(nt * 16 + m)] =
                    (_Float16)(dv[reg] * acc[nt][reg]);
        }
    }
}

// ---------- fused layer-1 aggregate + relu + @W2 : one wave per node ----------
// quad-edge scheme (R14 exact): lane owns feature quad fq=l&15; slot sub=l>>4
// processes edges 4k+sub; fixed-trip unrolled loop (dummy line-0 gathers for
// tail slots are L1-hot and cheaper than a divergent loop bound — R16 lesson).
__global__ __launch_bounds__(256) void k_agg_h2(const int2* __restrict__ offse,
                                                const int2* __restrict__ edata,
                                                const float* __restrict__ dinv,
                                                const _Float16* __restrict__ h,
                                                const float* __restrict__ b1,
                                                const float* __restrict__ W2,
                                                float* __restrict__ h2p, int N) {
    __shared__ int2 stage[4][64];
    int wv = threadIdx.x >> 6;
    int v = blockIdx.x * 4 + wv;
    if (v >= N) return;
    int l = threadIdx.x & 63;
    int sub = l >> 4;                  // edge slot 0..3
    unsigned fq = (unsigned)(l & 15);  // feature quad: features 4fq..4fq+3
    const hq4* hp = (const hq4*)h;     // hp[(src<<4)|fq] = 4 features (8B)

    float di = dinv[v];
    float a0 = 0.f, a1 = 0.f, a2 = 0.f, a3 = 0.f;
    if (sub == 0) {                    // self-loop: h'[v] = di*h[v]
        hq4 sv4 = hp[((unsigned)v << 4) | fq];
        a0 = (float)sv4.x; a1 = (float)sv4.y;
        a2 = (float)sv4.z; a3 = (float)sv4.w;
    }

    int2 oe = offse[v];
    for (int base = oe.x; base < oe.y; base += 64) {
        int idx = base + l;
        int2 pr;
        pr.x = 0; pr.y = 0;            // w=0 for lanes past the end
        if (idx < oe.y) pr = edata[idx];
        stage[wv][l] = pr;             // wave-private row; no block barrier needed
        int cnt = min(64, oe.y - base);
        int steps = (cnt + 3) >> 2;
#pragma unroll 4
        for (int k = 0; k < steps; ++k) {
            int2 em = stage[wv][4 * k + sub];
            float w = __int_as_float(em.y);
            hq4 hv = hp[((unsigned)em.x << 4) | fq];
            a0 += w * (float)hv.x;
            a1 += w * (float)hv.y;
            a2 += w * (float)hv.z;
            a3 += w * (float)hv.w;
        }
    }
    // reduce over the 4 edge slots (lanes sharing fq)
    a0 += __shfl_xor(a0, 16); a1 += __shfl_xor(a1, 16);
    a2 += __shfl_xor(a2, 16); a3 += __shfl_xor(a3, 16);
    a0 += __shfl_xor(a0, 32); a1 += __shfl_xor(a1, 32);
    a2 += __shfl_xor(a2, 32); a3 += __shfl_xor(a3, 32);

    if (sub == 0) {
        a0 = di * a0; a1 = di * a1; a2 = di * a2; a3 = di * a3;
        float s = fmaxf(a0 + b1[4 * fq], 0.f)     * W2[4 * fq]
                + fmaxf(a1 + b1[4 * fq + 1], 0.f) * W2[4 * fq + 1]
                + fmaxf(a2 + b1[4 * fq + 2], 0.f) * W2[4 * fq + 2]
                + fmaxf(a3 + b1[4 * fq + 3], 0.f) * W2[4 * fq + 3];
        s += __shfl_down(s, 8);
        s += __shfl_down(s, 4);
        s += __shfl_down(s, 2);
        s += __shfl_down(s, 1);
        if (fq == 0) h2p[v] = di * s;   // store dinv-scaled hidden
    }
}

// ---------- layer-2 aggregation: 16 lanes per node; h2p pre-scaled ----------
__global__ __launch_bounds__(256) void k_out(const int2* __restrict__ offse,
                                             const int2* __restrict__ edata,
                                             const float* __restrict__ dinv,
                                             const float* __restrict__ h2p,
                                             const float* __restrict__ b2,
                                             float* __restrict__ out, int N) {
    int t = blockIdx.x * 256 + threadIdx.x;
    int v = t >> 4;
    if (v >= N) return;
    int c = t & 15;
    int2 oe = offse[v];
    float s = 0.f;
    for (int i = oe.x + c; i < oe.y; i += 16) {
        int2 pr = edata[i];
        s += __int_as_float(pr.y) * h2p[(unsigned)pr.x];
    }
    s += __shfl_down(s, 8);
    s += __shfl_down(s, 4);
    s += __shfl_down(s, 2);
    s += __shfl_down(s, 1);
    if (c == 0) {
        float di = dinv[v];
        out[v] = b2[0] + di * (h2p[v] + s);   // h2p[v] = di*h2[v]
    }
}

extern "C" void kernel_launch(void* const* d_in, const int* in_sizes, int n_in,
                              void* d_out, int out_size, void* d_ws, size_t ws_size,
                              hipStream_t stream) {
    const float* x  = (const float*)d_in[0];
    const int*   ei = (const int*)d_in[1];
    const float* ew = (const float*)d_in[2];
    const float* W1 = (const float*)d_in[3];
    const float* b1 = (const float*)d_in[4];
    const float* W2 = (const float*)d_in[5];
    const float* b2 = (const float*)d_in[6];
    float* out = (float*)d_out;

    const int N = in_sizes[0] / DF;       // 100000
    const int E = in_sizes[2];            // 1600000
    const int* row = ei;                  // sources
    const int* col = ei + E;              // targets

    const int nbin = (N + 255) / 256;     // 391 coarse buckets
    const int nblk = (E + EPB - 1) / EPB; // 512 sort/scatter blocks

    // ---- workspace layout, ~34 MB (proven-safe budget ~40 MB) ----
    size_t    gsz   = (size_t)nbin * CAP;                 // gapped entry count
    int*      w32   = (int*)d_ws;
    int2*     edata = (int2*)w32;                         // gsz int2 = 16.0 MB
    int*      shreg = w32 + (size_t)2 * gsz;
    int2*     tmp   = (int2*)shreg;                       // build phase (16.0 MB)
    _Float16* h     = (_Float16*)shreg;                   // compute phase (12.8 MB)
    int*      p     = shreg + (size_t)2 * gsz;
    int*      cur   = p;  p += ((nbin) + 3) & ~3;         // nbin
    float*    dinv  = (float*)p;  p += N;                 // N
    float*    h2p   = (float*)p;  p += N;                 // N
    int2*     offse = (int2*)p;   p += 2 * N;             // N int2
    _Float16* W1f   = (_Float16*)p;                       // 8192 fp16 = 16 KB

    const int B = 256;
    int nstrip = (N + 15) / 16;
    int gGm  = (nstrip + 3) / 4;           // 4 waves (strips) per block
    int gAgg = (N + 3) / 4;
    int gN16 = (N * 16 + B - 1) / B;

    kPrep<<<32, B, 0, stream>>>(W1, W1f, cur, nbin);
    kA3<<<nblk, 512, 0, stream>>>(row, col, ew, cur, tmp, E, nbin);
    kB<<<nbin, B, 0, stream>>>(tmp, cur, edata, offse, dinv, N);
    k_gemm1<<<gGm, B, 0, stream>>>(x, W1f, dinv, h, N);
    k_agg_h2<<<gAgg, B, 0, stream>>>(offse, edata, dinv, h, b1, W2, h2p, N);
    k_out<<<gN16, B, 0, stream>>>(offse, edata, dinv, h2p, b2, out, N);
}

// Round 18
// 206.726 us; speedup vs baseline: 1.0259x; 1.0138x over previous
//
#include <hip/hip_runtime.h>
#include <stdint.h>

typedef float f4 __attribute__((ext_vector_type(4)));
typedef float f32x4 __attribute__((ext_vector_type(4)));
typedef _Float16 hq4 __attribute__((ext_vector_type(4)));
typedef _Float16 half8 __attribute__((ext_vector_type(8)));

#define DF 128    // input feature dim
#define HID 64    // hidden dim
#define EPB 4096  // edges per sort block (391 blocks of 512 threads, 8/thread)
#define CAP 5120  // slots per coarse bucket (avg 4096, max~4314 for seed-0 input)

// ---------- prep: zero cur + repack W1 into MFMA B-fragment order (fp16) ----------
__global__ __launch_bounds__(256) void kPrep(const float* __restrict__ W1,
                                             _Float16* __restrict__ W1f,
                                             int* __restrict__ cur, int nbin) {
    int t = blockIdx.x * 256 + threadIdx.x;   // 8192 threads
    if (t < nbin) cur[t] = 0;
    if (t < 8192) {
        int j     = t & 7;
        int lane  = (t >> 3) & 63;
        int ntile = (t >> 9) & 3;
        int kstep = t >> 11;
        int k = kstep * 32 + (lane >> 4) * 8 + j;
        int n = ntile * 16 + (lane & 15);
        W1f[t] = (_Float16)W1[k * 64 + n];
    }
}

// ---------- single-pass bucket scatter with block-local counting sort ----------
// 4096 edges/block sorted by coarse bin in LDS -> runs of ~10.5 edges per bin.
// R17 lesson: 391x4096 beats 512x3125 (longer write runs > residency balance).
__global__ __launch_bounds__(512) void kA3(const int* __restrict__ row,
                                           const int* __restrict__ col,
                                           const float* __restrict__ ew,
                                           int* __restrict__ cur,
                                           int2* __restrict__ tmp,
                                           int E, int nbin) {
    __shared__ int hist[512];
    __shared__ int pref[512];
    __shared__ int lbase[512];
    __shared__ int2 sv[EPB];   // 32 KB
    __shared__ int  sa[EPB];   // 16 KB
    int b = blockIdx.x, t = threadIdx.x;
    hist[t] = 0;
    __syncthreads();
    int s = b * EPB, e = min(E, s + EPB);
    int cnt = e - s;
    int  mybin[8], myrank[8];
    int2 myv[8];
#pragma unroll
    for (int k = 0; k < 8; ++k) {
        int i = s + t + k * 512;
        mybin[k] = -1;
        if (i < e) {
            int c = col[i];
            int bin = c >> 8;
            myv[k].x = row[i] | ((c & 255) << 24);   // src 17b | fine-col<<24
            myv[k].y = __float_as_int(ew[i]);
            mybin[k] = bin;
            myrank[k] = atomicAdd(&hist[bin], 1);
        }
    }
    __syncthreads();
    int val = hist[t];
    lbase[t] = val ? atomicAdd(&cur[t], val) + t * CAP : 0;  // absolute base (t==bin)
    for (int d = 1; d < 512; d <<= 1) {
        int x = (t >= d) ? hist[t - d] : 0;
        __syncthreads();
        hist[t] += x;
        __syncthreads();
    }
    pref[t] = hist[t] - val;   // exclusive prefix within block
    __syncthreads();
#pragma unroll
    for (int k = 0; k < 8; ++k) {
        if (mybin[k] >= 0) {
            int pos = pref[mybin[k]] + myrank[k];
            sv[pos] = myv[k];
            sa[pos] = lbase[mybin[k]] + myrank[k];
        }
    }
    __syncthreads();
    for (int i = t; i < cnt; i += 512) tmp[sa[i]] = sv[i];
}

// ---------- B: fine sort in LDS, coalesced edata write, fused deg/rsqrt ----------
__global__ __launch_bounds__(256) void kB(const int2* __restrict__ tmp,
                                          const int* __restrict__ cur,
                                          int2* __restrict__ edata,
                                          int2* __restrict__ offse,
                                          float* __restrict__ dinv,
                                          int N) {
    __shared__ int hist[256];
    __shared__ int basel[256];
    __shared__ int startl[256];
    __shared__ float degl[256];
    __shared__ int2 sorted[CAP];   // 40 KB
    int bin = blockIdx.x, t = threadIdx.x;
    int s = bin * CAP;
    int cnt = min(cur[bin], CAP);
    int e = s + cnt;

    hist[t] = 0;
    degl[t] = 0.f;
    __syncthreads();
    for (int i = s + t; i < e; i += 256) {
        int2 pr = tmp[i];
        int lo = ((unsigned)pr.x) >> 24;
        atomicAdd(&hist[lo], 1);
        atomicAdd(&degl[lo], __int_as_float(pr.y));
    }
    __syncthreads();
    int val = hist[t];
    __syncthreads();
    for (int d = 1; d < 256; d <<= 1) {
        int x = (t >= d) ? hist[t - d] : 0;
        __syncthreads();
        hist[t] += x;
        __syncthreads();
    }
    int loff = hist[t] - val;      // exclusive prefix within bucket (local)
    startl[t] = s + loff;
    basel[t]  = loff;
    __syncthreads();
    for (int i = s + t; i < e; i += 256) {
        int2 pr = tmp[i];
        int lo = ((unsigned)pr.x) >> 24;
        int pos = atomicAdd(&basel[lo], 1);
        int2 o;
        o.x = pr.x & 0x00FFFFFF;
        o.y = pr.y;
        sorted[pos] = o;
    }
    __syncthreads();
    for (int i = t; i < cnt; i += 256) edata[s + i] = sorted[i];
    int c = bin * 256 + t;
    if (c < N) {
        int2 oe;
        oe.x = startl[t];
        oe.y = startl[t] + val;
        offse[c] = oe;
        dinv[c] = rsqrtf(1.0f + degl[t]);   // deg >= 1 (self-loop)
    }
}

// ---------- h' = dinv[n] * (x @ W1)[n] via MFMA fp16, fp16 store ----------
__global__ __launch_bounds__(256) void k_gemm1(const float* __restrict__ x,
                                               const _Float16* __restrict__ W1f,
                                               const float* __restrict__ dinv,
                                               _Float16* __restrict__ h, int N) {
    int wave  = (blockIdx.x * 256 + threadIdx.x) >> 6;
    int nstrip = (N + 15) >> 4;
    if (wave >= nstrip) return;
    int node0 = wave << 4;
    int l = threadIdx.x & 63;
    int quad = l >> 4;
    int m = l & 15;
    int r = node0 + m;
    if (r >= N) r = N - 1;   // clamp (harmless duplicate load)

    const half8* bfrag = (const half8*)W1f;
    f32x4 acc[4];
#pragma unroll
    for (int nt = 0; nt < 4; ++nt) acc[nt] = (f32x4)(0.f);

#pragma unroll
    for (int kstep = 0; kstep < 4; ++kstep) {
        const f4* xr = (const f4*)(x + (size_t)r * DF + kstep * 32 + quad * 8);
        f4 a0 = xr[0], a1 = xr[1];
        half8 af;
        af[0] = (_Float16)a0.x; af[1] = (_Float16)a0.y;
        af[2] = (_Float16)a0.z; af[3] = (_Float16)a0.w;
        af[4] = (_Float16)a1.x; af[5] = (_Float16)a1.y;
        af[6] = (_Float16)a1.z; af[7] = (_Float16)a1.w;
#pragma unroll
        for (int nt = 0; nt < 4; ++nt) {
            half8 bf = bfrag[(kstep * 4 + nt) * 64 + l];
            acc[nt] = __builtin_amdgcn_mfma_f32_16x16x32_f16(af, bf, acc[nt], 0, 0, 0);
        }
    }

    float dv[4];
    int nodeb = node0 + quad * 4;
#pragma unroll
    for (int reg = 0; reg < 4; ++reg)
        dv[reg] = (nodeb + reg < N) ? dinv[nodeb + reg] : 0.f;
#pragma unroll
    for (int nt = 0; nt < 4; ++nt) {
#pragma unroll
        for (int reg = 0; reg < 4; ++reg) {
            int node = nodeb + reg;
            if (node < N)
                h[(unsigned)node * 64u + (unsigned)(nt * 16 + m)] =
                    (_Float16)(dv[reg] * acc[nt][reg]);
        }
    }
}

// ---------- fused layer-1 aggregate + relu + @W2 : one wave per node ----------
// quad-edge scheme (R14 exact): lane owns feature quad fq=l&15; slot sub=l>>4
// processes edges 4k+sub; fixed-trip unrolled loop (dummy line-0 gathers for
// tail slots are cheap; divergent bounds regressed — R16).
__global__ __launch_bounds__(256) void k_agg_h2(const int2* __restrict__ offse,
                                                const int2* __restrict__ edata,
                                                const float* __restrict__ dinv,
                                                const _Float16* __restrict__ h,
                                                const float* __restrict__ b1,
                                                const float* __restrict__ W2,
                                                float* __restrict__ h2p, int N) {
    __shared__ int2 stage[4][64];
    int wv = threadIdx.x >> 6;
    int v = blockIdx.x * 4 + wv;
    if (v >= N) return;
    int l = threadIdx.x & 63;
    int sub = l >> 4;                  // edge slot 0..3
    unsigned fq = (unsigned)(l & 15);  // feature quad: features 4fq..4fq+3
    const hq4* hp = (const hq4*)h;     // hp[(src<<4)|fq] = 4 features (8B)

    float di = dinv[v];
    float a0 = 0.f, a1 = 0.f, a2 = 0.f, a3 = 0.f;
    if (sub == 0) {                    // self-loop: h'[v] = di*h[v]
        hq4 sv4 = hp[((unsigned)v << 4) | fq];
        a0 = (float)sv4.x; a1 = (float)sv4.y;
        a2 = (float)sv4.z; a3 = (float)sv4.w;
    }

    int2 oe = offse[v];
    for (int base = oe.x; base < oe.y; base += 64) {
        int idx = base + l;
        int2 pr;
        pr.x = 0; pr.y = 0;            // w=0 for lanes past the end
        if (idx < oe.y) pr = edata[idx];
        stage[wv][l] = pr;             // wave-private row; no block barrier needed
        int cnt = min(64, oe.y - base);
        int steps = (cnt + 3) >> 2;
#pragma unroll 4
        for (int k = 0; k < steps; ++k) {
            int2 em = stage[wv][4 * k + sub];
            float w = __int_as_float(em.y);
            hq4 hv = hp[((unsigned)em.x << 4) | fq];
            a0 += w * (float)hv.x;
            a1 += w * (float)hv.y;
            a2 += w * (float)hv.z;
            a3 += w * (float)hv.w;
        }
    }
    // reduce over the 4 edge slots (lanes sharing fq)
    a0 += __shfl_xor(a0, 16); a1 += __shfl_xor(a1, 16);
    a2 += __shfl_xor(a2, 16); a3 += __shfl_xor(a3, 16);
    a0 += __shfl_xor(a0, 32); a1 += __shfl_xor(a1, 32);
    a2 += __shfl_xor(a2, 32); a3 += __shfl_xor(a3, 32);

    if (sub == 0) {
        a0 = di * a0; a1 = di * a1; a2 = di * a2; a3 = di * a3;
        float s = fmaxf(a0 + b1[4 * fq], 0.f)     * W2[4 * fq]
                + fmaxf(a1 + b1[4 * fq + 1], 0.f) * W2[4 * fq + 1]
                + fmaxf(a2 + b1[4 * fq + 2], 0.f) * W2[4 * fq + 2]
                + fmaxf(a3 + b1[4 * fq + 3], 0.f) * W2[4 * fq + 3];
        s += __shfl_down(s, 8);
        s += __shfl_down(s, 4);
        s += __shfl_down(s, 2);
        s += __shfl_down(s, 1);
        if (fq == 0) h2p[v] = di * s;   // store dinv-scaled hidden
    }
}

// ---------- layer-2 aggregation: 16 lanes per node; h2p pre-scaled ----------
__global__ __launch_bounds__(256) void k_out(const int2* __restrict__ offse,
                                             const int2* __restrict__ edata,
                                             const float* __restrict__ dinv,
                                             const float* __restrict__ h2p,
                                             const float* __restrict__ b2,
                                             float* __restrict__ out, int N) {
    int t = blockIdx.x * 256 + threadIdx.x;
    int v = t >> 4;
    if (v >= N) return;
    int c = t & 15;
    int2 oe = offse[v];
    float s = 0.f;
    for (int i = oe.x + c; i < oe.y; i += 16) {
        int2 pr = edata[i];
        s += __int_as_float(pr.y) * h2p[(unsigned)pr.x];
    }
    s += __shfl_down(s, 8);
    s += __shfl_down(s, 4);
    s += __shfl_down(s, 2);
    s += __shfl_down(s, 1);
    if (c == 0) {
        float di = dinv[v];
        out[v] = b2[0] + di * (h2p[v] + s);   // h2p[v] = di*h2[v]
    }
}

extern "C" void kernel_launch(void* const* d_in, const int* in_sizes, int n_in,
                              void* d_out, int out_size, void* d_ws, size_t ws_size,
                              hipStream_t stream) {
    const float* x  = (const float*)d_in[0];
    const int*   ei = (const int*)d_in[1];
    const float* ew = (const float*)d_in[2];
    const float* W1 = (const float*)d_in[3];
    const float* b1 = (const float*)d_in[4];
    const float* W2 = (const float*)d_in[5];
    const float* b2 = (const float*)d_in[6];
    float* out = (float*)d_out;

    const int N = in_sizes[0] / DF;       // 100000
    const int E = in_sizes[2];            // 1600000
    const int* row = ei;                  // sources
    const int* col = ei + E;              // targets

    const int nbin = (N + 255) / 256;     // 391 coarse buckets
    const int nblk = (E + EPB - 1) / EPB; // 391 sort/scatter blocks

    // ---- workspace layout, ~34 MB (proven-safe budget ~40 MB) ----
    size_t    gsz   = (size_t)nbin * CAP;                 // gapped entry count
    int*      w32   = (int*)d_ws;
    int2*     edata = (int2*)w32;                         // gsz int2 = 16.0 MB
    int*      shreg = w32 + (size_t)2 * gsz;
    int2*     tmp   = (int2*)shreg;                       // build phase (16.0 MB)
    _Float16* h     = (_Float16*)shreg;                   // compute phase (12.8 MB)
    int*      p     = shreg + (size_t)2 * gsz;
    int*      cur   = p;  p += ((nbin) + 3) & ~3;         // nbin
    float*    dinv  = (float*)p;  p += N;                 // N
    float*    h2p   = (float*)p;  p += N;                 // N
    int2*     offse = (int2*)p;   p += 2 * N;             // N int2
    _Float16* W1f   = (_Float16*)p;                       // 8192 fp16 = 16 KB

    const int B = 256;
    int nstrip = (N + 15) / 16;
    int gGm  = (nstrip + 3) / 4;           // 4 waves (strips) per block
    int gAgg = (N + 3) / 4;
    int gN16 = (N * 16 + B - 1) / B;

    kPrep<<<32, B, 0, stream>>>(W1, W1f, cur, nbin);
    kA3<<<nblk, 512, 0, stream>>>(row, col, ew, cur, tmp, E, nbin);
    kB<<<nbin, B, 0, stream>>>(tmp, cur, edata, offse, dinv, N);
    k_gemm1<<<gGm, B, 0, stream>>>(x, W1f, dinv, h, N);
    k_agg_h2<<<gAgg, B, 0, stream>>>(offse, edata, dinv, h, b1, W2, h2p, N);
    k_out<<<gN16, B, 0, stream>>>(offse, edata, dinv, h2p, b2, out, N);
}